// Round 15
// baseline (36.444 us; speedup 1.0000x reference)
//
#include <hip/hip_runtime.h>

#define NPTS 4096
#define BATCH 8
#define BLK 256
#define PPT 16                       // p-points per thread
#define NPB (BLK * PPT)              // 4096 p-points per block
#define MCH 128                      // q-points staged in LDS per block
#define NCHUNK (NPTS / MCH)          // 32
#define PGRP (NPTS / NPB)            // 1
#define FREG (NPTS / 4 / BLK)        // 4 float4 per finalize thread

typedef float v2 __attribute__((ext_vector_type(2)));

// ---------------------------------------------------------------------------
// Kernel 1: partial min over one q-chunk. grid = (1, 8, 64) = 512 blocks,
// 4 waves/block -> 8 waves/CU (2/SIMD) -- same occupancy as the R9 champion,
// but PPT=16 halves LDS instructions (128 ds_read_b128/wave) and gives each
// 4-read group 128 pk-VALU instrs to hide under. LDS is SoA float4 planes of
// {-2qx},{-2qy},{-2qz},{|q|^2}; inner loop is packed-fp32 fma (2 FMA/instr).
// Also zeroes the finalize ticket (stream order precedes dispatch 2).
// ---------------------------------------------------------------------------
__global__ __launch_bounds__(BLK, 2) void dmin_kernel(
    const float* __restrict__ X, const float* __restrict__ Y,
    float* __restrict__ partial, unsigned int* __restrict__ ticket) {
  if (blockIdx.x == 0 && blockIdx.y == 0 && blockIdx.z == 0 &&
      threadIdx.x == 0) {
    __hip_atomic_store(ticket, 0u, __ATOMIC_RELAXED, __HIP_MEMORY_SCOPE_AGENT);
  }

  const int pg    = blockIdx.x;
  const int b     = blockIdx.y;
  const int chunk = blockIdx.z & (NCHUNK - 1);
  const int dir   = blockIdx.z >> 5;
  const float* pts = dir ? Y : X;  // set we compute mins for
  const float* oth = dir ? X : Y;  // set we min over

  __shared__ float4 SQ[4][MCH / 4];  // 2 KB, SoA planes
  const float* othb = oth + ((size_t)b * NPTS + (size_t)chunk * MCH) * 3;
  if (threadIdx.x < MCH) {
    const int i = threadIdx.x;
    float qx = othb[3 * i], qy = othb[3 * i + 1], qz = othb[3 * i + 2];
    ((float*)&SQ[0][0])[i] = -2.f * qx;
    ((float*)&SQ[1][0])[i] = -2.f * qy;
    ((float*)&SQ[2][0])[i] = -2.f * qz;
    ((float*)&SQ[3][0])[i] = qx * qx + qy * qy + qz * qz;
  }
  __syncthreads();

  const int n0 = pg * NPB + threadIdx.x * PPT;  // 16 consecutive p-points
  // 48 consecutive floats, 192B-aligned -> 12 float4 loads
  const float4* pv4 = (const float4*)(pts + ((size_t)b * NPTS + n0) * 3);
  float px[PPT], py[PPT], pz[PPT];
#pragma unroll
  for (int g = 0; g < 4; ++g) {  // each group of 3 float4 = 4 points
    float4 A = pv4[3 * g], B = pv4[3 * g + 1], C = pv4[3 * g + 2];
    px[4 * g + 0] = A.x; py[4 * g + 0] = A.y; pz[4 * g + 0] = A.z;
    px[4 * g + 1] = A.w; py[4 * g + 1] = B.x; pz[4 * g + 1] = B.y;
    px[4 * g + 2] = B.z; py[4 * g + 2] = B.w; pz[4 * g + 2] = C.x;
    px[4 * g + 3] = C.y; py[4 * g + 3] = C.z; pz[4 * g + 3] = C.w;
  }

  float acc0[PPT], acc1[PPT];
#pragma unroll
  for (int i = 0; i < PPT; ++i) { acc0[i] = 3.4e38f; acc1[i] = 3.4e38f; }

#pragma unroll 2
  for (int m = 0; m < MCH; m += 4) {
    const int j = m >> 2;
    float4 x4 = SQ[0][j], y4 = SQ[1][j], z4 = SQ[2][j], w4 = SQ[3][j];
    v2 x01 = {x4.x, x4.y}, x23 = {x4.z, x4.w};
    v2 y01 = {y4.x, y4.y}, y23 = {y4.z, y4.w};
    v2 z01 = {z4.x, z4.y}, z23 = {z4.z, z4.w};
    v2 w01 = {w4.x, w4.y}, w23 = {w4.z, w4.w};
#pragma unroll
    for (int pp = 0; pp < PPT; ++pp) {
      v2 a = {px[pp], px[pp]}, bb = {py[pp], py[pp]}, c = {pz[pp], pz[pp]};
      v2 d01 = __builtin_elementwise_fma(a, x01,
               __builtin_elementwise_fma(bb, y01,
               __builtin_elementwise_fma(c, z01, w01)));
      v2 d23 = __builtin_elementwise_fma(a, x23,
               __builtin_elementwise_fma(bb, y23,
               __builtin_elementwise_fma(c, z23, w23)));
      acc0[pp] = fminf(fminf(acc0[pp], d01.x), d01.y);  // v_min3
      acc1[pp] = fminf(fminf(acc1[pp], d23.x), d23.y);  // v_min3
    }
  }

  float r[PPT];
#pragma unroll
  for (int pp = 0; pp < PPT; ++pp) {
    float c = px[pp] * px[pp] + py[pp] * py[pp] + pz[pp] * pz[pp];
    r[pp] = fminf(acc0[pp], acc1[pp]) + c;
  }
  float* dst = &partial[(((size_t)chunk * 2 + dir) * BATCH + b) * NPTS + n0];
#pragma unroll
  for (int g = 0; g < 4; ++g) {
    ((float4*)dst)[g] =
        make_float4(r[4 * g], r[4 * g + 1], r[4 * g + 2], r[4 * g + 3]);
  }
}

// ---------------------------------------------------------------------------
// Kernel 2: 16 blocks, block w = (dir,b). 32-way chunk-min in registers,
// fused sum/ssq (one-pass ddof=1 var), strict mask (v-mean > -0.5*std),
// fixed-order reductions -> res[w]. Last block (ticket) sums res[0..15] in
// fixed index order -> out[0]. No memset, no spin-wait, bit-deterministic.
// ---------------------------------------------------------------------------
__global__ __launch_bounds__(BLK) void finalize_kernel(
    const float* __restrict__ partial, float* __restrict__ res,
    unsigned int* __restrict__ ticket, float* __restrict__ out) {
  const int w    = blockIdx.x;   // dir*8 + b
  const int dir  = w >> 3;
  const int b    = w & 7;
  const int wid  = threadIdx.x >> 6;
  const int lane = threadIdx.x & 63;

  __shared__ float rA[4], rB[4], rC[4], rD[4];

  const float4* pv = (const float4*)partial;
  const size_t vbase = ((size_t)dir * BATCH + b) * (NPTS / 4);
  const size_t cstr  = (size_t)2 * BATCH * (NPTS / 4);

  float4 mreg[FREG];  // this thread's 4 minned float4s, kept in registers
  float sum = 0.0f, ssq = 0.0f;
#pragma unroll
  for (int k = 0; k < FREG; ++k) {
    const int i = threadIdx.x + k * BLK;
    float4 m = pv[vbase + i];
#pragma unroll 8
    for (int c = 1; c < NCHUNK; ++c) {
      float4 t = pv[vbase + (size_t)c * cstr + i];
      m.x = fminf(m.x, t.x); m.y = fminf(m.y, t.y);
      m.z = fminf(m.z, t.z); m.w = fminf(m.w, t.w);
    }
    mreg[k] = m;
    sum += (m.x + m.y) + (m.z + m.w);
    ssq += (m.x * m.x + m.y * m.y) + (m.z * m.z + m.w * m.w);
  }
  for (int off = 32; off; off >>= 1) sum += __shfl_xor(sum, off, 64);
  for (int off = 32; off; off >>= 1) ssq += __shfl_xor(ssq, off, 64);
  if (lane == 0) { rA[wid] = sum; rB[wid] = ssq; }
  __syncthreads();
  sum = ((rA[0] + rA[1]) + (rA[2] + rA[3]));  // fixed order: deterministic
  ssq = ((rB[0] + rB[1]) + (rB[2] + rB[3]));
  const float mean = sum / (float)NPTS;
  const float var  = (ssq - (float)NPTS * mean * mean) / (float)(NPTS - 1);
  const float neg_thr = -0.5f * sqrtf(fmaxf(var, 0.0f));

  float ksum = 0.0f, kcnt = 0.0f;
#pragma unroll
  for (int k = 0; k < FREG; ++k) {
    float4 t = mreg[k];
    if (t.x - mean > neg_thr) { ksum += t.x; kcnt += 1.0f; }
    if (t.y - mean > neg_thr) { ksum += t.y; kcnt += 1.0f; }
    if (t.z - mean > neg_thr) { ksum += t.z; kcnt += 1.0f; }
    if (t.w - mean > neg_thr) { ksum += t.w; kcnt += 1.0f; }
  }
  for (int off = 32; off; off >>= 1) ksum += __shfl_xor(ksum, off, 64);
  for (int off = 32; off; off >>= 1) kcnt += __shfl_xor(kcnt, off, 64);
  if (lane == 0) { rC[wid] = ksum; rD[wid] = kcnt; }
  __syncthreads();

  if (threadIdx.x == 0) {
    ksum = ((rC[0] + rC[1]) + (rC[2] + rC[3]));
    kcnt = ((rD[0] + rD[1]) + (rD[2] + rD[3]));
    __hip_atomic_store(&res[w], ksum / kcnt, __ATOMIC_RELAXED,
                       __HIP_MEMORY_SCOPE_AGENT);
    __threadfence();  // release: res[w] visible before ticket bump
    unsigned int old = atomicAdd(ticket, 1u);  // device-scope by default
    if (old == 15u) {
      __threadfence();  // acquire: all res[] writes visible
      float tot = 0.0f;
      for (int i = 0; i < 16; ++i) {  // fixed order: bit-deterministic
        tot += __hip_atomic_load(&res[i], __ATOMIC_RELAXED,
                                 __HIP_MEMORY_SCOPE_AGENT);
      }
      out[0] = tot / (float)BATCH;
    }
  }
}

extern "C" void kernel_launch(void* const* d_in, const int* in_sizes, int n_in,
                              void* d_out, int out_size, void* d_ws, size_t ws_size,
                              hipStream_t stream) {
  const float* x = (const float*)d_in[0];
  const float* y = (const float*)d_in[1];
  float* out = (float*)d_out;
  float* partial = (float*)d_ws;                       // 32*2*8*4096*4B = 8 MB
  float* res = partial + (size_t)NCHUNK * 2 * BATCH * NPTS;  // 16 floats
  unsigned int* ticket = (unsigned int*)(res + 16);          // 1 uint

  dim3 g1(PGRP, BATCH, 2 * NCHUNK);
  dmin_kernel<<<g1, BLK, 0, stream>>>(x, y, partial, ticket);
  finalize_kernel<<<16, BLK, 0, stream>>>(partial, res, ticket, out);
}

// Round 16
// 32.611 us; speedup vs baseline: 1.1176x; 1.1176x over previous
//
#include <hip/hip_runtime.h>

#define NPTS 4096
#define BATCH 8
#define BLK 256
#define PPT 8                        // p-points per thread
#define NPB (BLK * PPT)              // 2048 p-points per block
#define MCH 256                      // q-points staged in LDS per block
#define NCHUNK (NPTS / MCH)          // 16
#define PGRP (NPTS / NPB)            // 2
#define FREG (NPTS / 4 / BLK)        // 4 float4 per finalize thread

// ---------------------------------------------------------------------------
// Kernel 1: partial min over one q-chunk. R9 champion config (512 blocks,
// MCH=256, PPT=8, scalar fmaf/min3 AoS math -- bit-identical results), with
// ONE change: explicit depth-1 register prefetch of the next 4-q group so the
// ds_read_b128 latency (~120 cyc) overlaps the ~60-VALU compute of the
// current group instead of stalling the wave (only 2 waves/SIMD available).
// ---------------------------------------------------------------------------
__global__ __launch_bounds__(BLK, 2) void dmin_kernel(
    const float* __restrict__ X, const float* __restrict__ Y,
    float* __restrict__ partial, unsigned int* __restrict__ ticket) {
  if (blockIdx.x == 0 && blockIdx.y == 0 && blockIdx.z == 0 &&
      threadIdx.x == 0) {
    __hip_atomic_store(ticket, 0u, __ATOMIC_RELAXED, __HIP_MEMORY_SCOPE_AGENT);
  }

  const int pg    = blockIdx.x;
  const int b     = blockIdx.y;
  const int chunk = blockIdx.z & (NCHUNK - 1);
  const int dir   = blockIdx.z >> 4;
  const float* pts = dir ? Y : X;  // set we compute mins for
  const float* oth = dir ? X : Y;  // set we min over

  __shared__ float4 s[MCH];  // 4 KB, AoS (-2qx,-2qy,-2qz,|q|^2)
  const float* othb = oth + ((size_t)b * NPTS + (size_t)chunk * MCH) * 3;
  {
    const int i = threadIdx.x;  // MCH == BLK: one q per thread
    float qx = othb[3 * i], qy = othb[3 * i + 1], qz = othb[3 * i + 2];
    s[i] = make_float4(-2.f * qx, -2.f * qy, -2.f * qz,
                       qx * qx + qy * qy + qz * qz);
  }
  __syncthreads();

  const int n0 = pg * NPB + threadIdx.x * PPT;  // 8 consecutive p-points
  const float4* pv4 = (const float4*)(pts + ((size_t)b * NPTS + n0) * 3);
  const float4 A = pv4[0], B = pv4[1], C = pv4[2];
  const float4 D = pv4[3], E = pv4[4], F = pv4[5];
  float px[PPT], py[PPT], pz[PPT];
  px[0] = A.x; py[0] = A.y; pz[0] = A.z;
  px[1] = A.w; py[1] = B.x; pz[1] = B.y;
  px[2] = B.z; py[2] = B.w; pz[2] = C.x;
  px[3] = C.y; py[3] = C.z; pz[3] = C.w;
  px[4] = D.x; py[4] = D.y; pz[4] = D.z;
  px[5] = D.w; py[5] = E.x; pz[5] = E.y;
  px[6] = E.z; py[6] = E.w; pz[6] = F.x;
  px[7] = F.y; py[7] = F.z; pz[7] = F.w;

  float acc[2 * PPT];
#pragma unroll
  for (int i = 0; i < 2 * PPT; ++i) acc[i] = 3.4e38f;

#define COMPUTE(q0, q1, q2, q3)                                               \
  {                                                                           \
    _Pragma("unroll")                                                         \
    for (int pp = 0; pp < PPT; ++pp) {                                        \
      float d0 = fmaf(px[pp], q0.x,                                           \
                 fmaf(py[pp], q0.y, fmaf(pz[pp], q0.z, q0.w)));               \
      float d1 = fmaf(px[pp], q1.x,                                           \
                 fmaf(py[pp], q1.y, fmaf(pz[pp], q1.z, q1.w)));               \
      float d2 = fmaf(px[pp], q2.x,                                           \
                 fmaf(py[pp], q2.y, fmaf(pz[pp], q2.z, q2.w)));               \
      float d3 = fmaf(px[pp], q3.x,                                           \
                 fmaf(py[pp], q3.y, fmaf(pz[pp], q3.z, q3.w)));               \
      acc[2 * pp]     = fminf(fminf(acc[2 * pp], d0), d1);     /* v_min3 */   \
      acc[2 * pp + 1] = fminf(fminf(acc[2 * pp + 1], d2), d3); /* v_min3 */   \
    }                                                                         \
  }

  // Depth-1 software pipeline: loads for group m+4 issue before the compute
  // of group m, so lgkmcnt waits land after ~120 cycles of useful VALU work.
  float4 c0 = s[0], c1 = s[1], c2 = s[2], c3 = s[3];
#pragma unroll 2
  for (int m = 0; m < MCH - 4; m += 4) {
    float4 t0 = s[m + 4], t1 = s[m + 5], t2 = s[m + 6], t3 = s[m + 7];
    COMPUTE(c0, c1, c2, c3);
    c0 = t0; c1 = t1; c2 = t2; c3 = t3;
  }
  COMPUTE(c0, c1, c2, c3);
#undef COMPUTE

  float r[PPT];
#pragma unroll
  for (int pp = 0; pp < PPT; ++pp) {
    float c = px[pp] * px[pp] + py[pp] * py[pp] + pz[pp] * pz[pp];
    r[pp] = fminf(acc[2 * pp], acc[2 * pp + 1]) + c;
  }
  float* dst = &partial[(((size_t)chunk * 2 + dir) * BATCH + b) * NPTS + n0];
  ((float4*)dst)[0] = make_float4(r[0], r[1], r[2], r[3]);
  ((float4*)dst)[1] = make_float4(r[4], r[5], r[6], r[7]);
}

// ---------------------------------------------------------------------------
// Kernel 2: 16 blocks, block w = (dir,b). 16-way chunk-min in registers,
// fused sum/ssq (one-pass ddof=1 var), strict mask (v-mean > -0.5*std),
// fixed-order reductions -> res[w]. Last block (ticket) sums res[0..15] in
// fixed index order -> out[0]. No memset, no spin-wait, bit-deterministic.
// ---------------------------------------------------------------------------
__global__ __launch_bounds__(BLK) void finalize_kernel(
    const float* __restrict__ partial, float* __restrict__ res,
    unsigned int* __restrict__ ticket, float* __restrict__ out) {
  const int w    = blockIdx.x;   // dir*8 + b
  const int dir  = w >> 3;
  const int b    = w & 7;
  const int wid  = threadIdx.x >> 6;
  const int lane = threadIdx.x & 63;

  __shared__ float rA[4], rB[4], rC[4], rD[4];

  const float4* pv = (const float4*)partial;
  const size_t vbase = ((size_t)dir * BATCH + b) * (NPTS / 4);
  const size_t cstr  = (size_t)2 * BATCH * (NPTS / 4);

  float4 mreg[FREG];  // this thread's 4 minned float4s, kept in registers
  float sum = 0.0f, ssq = 0.0f;
#pragma unroll
  for (int k = 0; k < FREG; ++k) {
    const int i = threadIdx.x + k * BLK;
    float4 m = pv[vbase + i];
#pragma unroll
    for (int c = 1; c < NCHUNK; ++c) {
      float4 t = pv[vbase + (size_t)c * cstr + i];
      m.x = fminf(m.x, t.x); m.y = fminf(m.y, t.y);
      m.z = fminf(m.z, t.z); m.w = fminf(m.w, t.w);
    }
    mreg[k] = m;
    sum += (m.x + m.y) + (m.z + m.w);
    ssq += (m.x * m.x + m.y * m.y) + (m.z * m.z + m.w * m.w);
  }
  for (int off = 32; off; off >>= 1) sum += __shfl_xor(sum, off, 64);
  for (int off = 32; off; off >>= 1) ssq += __shfl_xor(ssq, off, 64);
  if (lane == 0) { rA[wid] = sum; rB[wid] = ssq; }
  __syncthreads();
  sum = ((rA[0] + rA[1]) + (rA[2] + rA[3]));  // fixed order: deterministic
  ssq = ((rB[0] + rB[1]) + (rB[2] + rB[3]));
  const float mean = sum / (float)NPTS;
  const float var  = (ssq - (float)NPTS * mean * mean) / (float)(NPTS - 1);
  const float neg_thr = -0.5f * sqrtf(fmaxf(var, 0.0f));

  float ksum = 0.0f, kcnt = 0.0f;
#pragma unroll
  for (int k = 0; k < FREG; ++k) {
    float4 t = mreg[k];
    if (t.x - mean > neg_thr) { ksum += t.x; kcnt += 1.0f; }
    if (t.y - mean > neg_thr) { ksum += t.y; kcnt += 1.0f; }
    if (t.z - mean > neg_thr) { ksum += t.z; kcnt += 1.0f; }
    if (t.w - mean > neg_thr) { ksum += t.w; kcnt += 1.0f; }
  }
  for (int off = 32; off; off >>= 1) ksum += __shfl_xor(ksum, off, 64);
  for (int off = 32; off; off >>= 1) kcnt += __shfl_xor(kcnt, off, 64);
  if (lane == 0) { rC[wid] = ksum; rD[wid] = kcnt; }
  __syncthreads();

  if (threadIdx.x == 0) {
    ksum = ((rC[0] + rC[1]) + (rC[2] + rC[3]));
    kcnt = ((rD[0] + rD[1]) + (rD[2] + rD[3]));
    __hip_atomic_store(&res[w], ksum / kcnt, __ATOMIC_RELAXED,
                       __HIP_MEMORY_SCOPE_AGENT);
    __threadfence();  // release: res[w] visible before ticket bump
    unsigned int old = atomicAdd(ticket, 1u);  // device-scope by default
    if (old == 15u) {
      __threadfence();  // acquire: all res[] writes visible
      float tot = 0.0f;
      for (int i = 0; i < 16; ++i) {  // fixed order: bit-deterministic
        tot += __hip_atomic_load(&res[i], __ATOMIC_RELAXED,
                                 __HIP_MEMORY_SCOPE_AGENT);
      }
      out[0] = tot / (float)BATCH;
    }
  }
}

extern "C" void kernel_launch(void* const* d_in, const int* in_sizes, int n_in,
                              void* d_out, int out_size, void* d_ws, size_t ws_size,
                              hipStream_t stream) {
  const float* x = (const float*)d_in[0];
  const float* y = (const float*)d_in[1];
  float* out = (float*)d_out;
  float* partial = (float*)d_ws;                       // 16*2*8*4096*4B = 4 MB
  float* res = partial + (size_t)NCHUNK * 2 * BATCH * NPTS;  // 16 floats
  unsigned int* ticket = (unsigned int*)(res + 16);          // 1 uint

  dim3 g1(PGRP, BATCH, 2 * NCHUNK);
  dmin_kernel<<<g1, BLK, 0, stream>>>(x, y, partial, ticket);
  finalize_kernel<<<16, BLK, 0, stream>>>(partial, res, ticket, out);
}